// Round 1
// baseline (287.270 us; speedup 1.0000x reference)
//
#include <hip/hip_runtime.h>

typedef unsigned int u32;
typedef unsigned short u16;
typedef __bf16 bf16x8 __attribute__((ext_vector_type(8)));
typedef float f32x4 __attribute__((ext_vector_type(4)));

#define HIDDEN 2048
#define HEADS 16
#define HDIM 128
#define SEQ 1024
#define BATCH 2
#define ROWS (BATCH*SEQ)
#define SCALE 0.08838834764831845f   /* 128^-0.5 */
#define GSC 0.1f

__device__ __forceinline__ u16 f2bf(float f) {
    u32 x = __builtin_bit_cast(u32, f);
    x += 0x7fffu + ((x >> 16) & 1u);          // RNE
    return (u16)(x >> 16);
}
__device__ __forceinline__ float bf2f(u16 u) {
    return __builtin_bit_cast(float, ((u32)u) << 16);
}
__device__ __forceinline__ void gld_lds16(const void* g, void* l) {
    __builtin_amdgcn_global_load_lds((const __attribute__((address_space(1))) u32*)g,
                                     (__attribute__((address_space(3))) u32*)l, 16, 0, 0);
}

// ---------------- fp32 -> bf16 convert (x) ----------------
__global__ void k_cvt(const float* __restrict__ in, u16* __restrict__ out_, int n) {
    int i = (blockIdx.x * 256 + threadIdx.x) * 4;
    if (i >= n) return;
    float4 v = *(const float4*)(in + i);
    uint2 r;
    r.x = (u32)f2bf(v.x) | ((u32)f2bf(v.y) << 16);
    r.y = (u32)f2bf(v.z) | ((u32)f2bf(v.w) << 16);
    *(uint2*)(out_ + i) = r;
}

// ---------------- W [K][N] fp32 -> Wt [N][K] bf16 ----------------
__global__ void k_wt(const float* __restrict__ W, u16* __restrict__ Wt) {
    __shared__ float t[32][33];
    const int bx = blockIdx.x * 32, by = blockIdx.y * 32;
    const int tx = threadIdx.x, ty = threadIdx.y;
#pragma unroll
    for (int yy = 0; yy < 32; yy += 8)
        t[ty + yy][tx] = W[(size_t)(by + ty + yy) * HIDDEN + bx + tx];
    __syncthreads();
#pragma unroll
    for (int yy = 0; yy < 32; yy += 8)
        Wt[(size_t)(bx + ty + yy) * HIDDEN + by + tx] = f2bf(t[tx][ty + yy]);
}

// ---------------- RoPE tables [S][64] ----------------
__global__ void k_rope_tab(float* __restrict__ cosT, float* __restrict__ sinT) {
    const int i = blockIdx.x * 256 + threadIdx.x;   // 65536
    const int s = i >> 6, d = i & 63;
    const float inv = expf(-(float)d * 0.14391156831f);  // ln(10000)/64
    const float fr = (float)s * inv;
    cosT[i] = cosf(fr);
    sinT[i] = sinf(fr);
}

// ---------------- RoPE applied in place to qraw,kraw (bf16 [2048][2048]) ----------------
__global__ void k_rope_apply(u16* __restrict__ q, u16* __restrict__ k,
                             const float* __restrict__ cosT, const float* __restrict__ sinT) {
    const int i = blockIdx.x * 256 + threadIdx.x;   // 2M = 2048*16*64
    const int row = i >> 10;
    const int hd = i & 1023;
    const int h = hd >> 6, d = hd & 63;
    const int s = row & (SEQ - 1);
    const float c = cosT[s * 64 + d], sn = sinT[s * 64 + d];
    const size_t o1 = (size_t)row * HIDDEN + h * HDIM + d;
    const size_t o2 = o1 + 64;
    float x1 = bf2f(q[o1]), x2 = bf2f(q[o2]);
    q[o1] = f2bf(x1 * c - x2 * sn);
    q[o2] = f2bf(x2 * c + x1 * sn);
    float y1 = bf2f(k[o1]), y2 = bf2f(k[o2]);
    k[o1] = f2bf(y1 * c - y2 * sn);
    k[o2] = f2bf(y2 * c + y1 * sn);
}

// ---------------- v [2048][2048] -> vT [BH][128][1024] ----------------
__global__ void k_vt(const u16* __restrict__ v, u16* __restrict__ vT) {
    __shared__ u16 t[32][33];
    const int s0 = blockIdx.x * 32, d0 = blockIdx.y * 32;
    const int bh = blockIdx.z;
    const int b = bh >> 4, h = bh & 15;
    const int tx = threadIdx.x, ty = threadIdx.y;
#pragma unroll
    for (int yy = 0; yy < 32; yy += 8)
        t[ty + yy][tx] = v[(size_t)(b * SEQ + s0 + ty + yy) * HIDDEN + h * HDIM + d0 + tx];
    __syncthreads();
#pragma unroll
    for (int yy = 0; yy < 32; yy += 8)
        vT[((size_t)bh * HDIM + d0 + ty + yy) * SEQ + s0 + tx] = t[tx][ty + yy];
}

// ---------------- GEMM: C[M][N] = A[M][K] * Bt[N][K]^T  (m97 structure) ----------------
// MODE 0: z-selected Bt/C, bf16 out.  MODE 1: Bt=B0, fp32 out + bias.
template <int MODE>
__global__ __launch_bounds__(256) void k_gemm(
    const u16* __restrict__ A,
    const u16* __restrict__ B0, const u16* __restrict__ B1, const u16* __restrict__ B2,
    u16* __restrict__ C0, u16* __restrict__ C1, u16* __restrict__ C2,
    float* __restrict__ Cf, const float* __restrict__ bias) {
    constexpr int K = HIDDEN, N = HIDDEN;
    const u16* Bt = B0;
    u16* Cb = C0;
    if (MODE == 0) {
        int z = blockIdx.z;
        Bt = (z == 0) ? B0 : (z == 1) ? B1 : B2;
        Cb = (z == 0) ? C0 : (z == 1) ? C1 : C2;
    }
    __shared__ __align__(16) u16 As[128 * 64];
    __shared__ __align__(16) u16 Bs[128 * 64];
    const int tid = threadIdx.x;
    const int ln = tid & 63, w = tid >> 6;
    const int wr = w >> 1, wc = w & 1;
    const int g = ln >> 4, l15 = ln & 15;
    const int m0 = blockIdx.x * 128, n0 = blockIdx.y * 128;
    const int srow = tid >> 3, scol = (tid & 7) * 8;
    f32x4 acc[4][4] = {};
    for (int kk = 0; kk < K; kk += 64) {
#pragma unroll
        for (int c = 0; c < 4; ++c) {
            gld_lds16(A + (size_t)(m0 + c * 32 + srow) * K + kk + scol, &As[c * 2048 + tid * 8]);
            gld_lds16(Bt + (size_t)(n0 + c * 32 + srow) * K + kk + scol, &Bs[c * 2048 + tid * 8]);
        }
        __syncthreads();
#pragma unroll
        for (int ks = 0; ks < 2; ++ks) {
            bf16x8 a[4], b[4];
#pragma unroll
            for (int m = 0; m < 4; ++m)
                a[m] = *(const bf16x8*)&As[(wr * 64 + m * 16 + l15) * 64 + ks * 32 + g * 8];
#pragma unroll
            for (int n = 0; n < 4; ++n)
                b[n] = *(const bf16x8*)&Bs[(wc * 64 + n * 16 + l15) * 64 + ks * 32 + g * 8];
#pragma unroll
            for (int m = 0; m < 4; ++m)
#pragma unroll
                for (int n = 0; n < 4; ++n)
                    acc[m][n] = __builtin_amdgcn_mfma_f32_16x16x32_bf16(a[m], b[n], acc[m][n], 0, 0, 0);
        }
        __syncthreads();
    }
#pragma unroll
    for (int m = 0; m < 4; ++m)
#pragma unroll
        for (int n = 0; n < 4; ++n) {
            const int col = n0 + wc * 64 + n * 16 + l15;
#pragma unroll
            for (int j = 0; j < 4; ++j) {
                const int row = m0 + wr * 64 + m * 16 + g * 4 + j;
                if (MODE == 0)
                    Cb[(size_t)row * N + col] = f2bf(acc[m][n][j]);
                else
                    Cf[(size_t)row * N + col] = acc[m][n][j] + bias[col];
            }
        }
}

// ---------------- fused causal attention with governance bias ----------------
// grid (16, 32); qt mirrored so each CU's two blocks total 17 k-tiles.
// Swapped QK^T: S^T[k][q] = mfma(K_frag, Q_frag) -> lane's q = lane&15 -> float4 mask loads.
__global__ __launch_bounds__(256) void k_attn(
    const u16* __restrict__ qraw, const u16* __restrict__ kraw, const u16* __restrict__ vT,
    const float* __restrict__ pm, const float* __restrict__ po, const float* __restrict__ mw,
    u16* __restrict__ attnb) {
    __shared__ __align__(16) u16 Ks[64 * 128];
    __shared__ __align__(16) u16 Vs[128 * 64];
    __shared__ __align__(16) u16 Pl[4][16 * 72];   // per-wave P, padded stride
    const int tid = threadIdx.x;
    const int ln = tid & 63, w = tid >> 6;
    const int g = ln >> 4, q15 = ln & 15;
    const int y = blockIdx.y;
    const int b = y >> 4, h = y & 15;
    const int qt = (y < 16) ? (int)blockIdx.x : (15 - (int)blockIdx.x);
    const int q0 = qt * 64;
    const int qw = q0 + w * 16;
    const int qg = qw + q15;
    // staging (pre-swizzled global source; linear LDS dest per rule 21 + m173)
    const int k_srow = tid >> 4;
    const int k_scol = ((tid & 15) * 8) ^ (((tid >> 4) & 7) << 3);
    const int v_srow = tid >> 3;
    const int v_scol = ((tid & 7) * 8) ^ (((tid >> 3) & 7) << 3);
    const int sw = (q15 & 7) << 3;   // read-side XOR (elements)
    // Q fragments in registers
    bf16x8 qf[4];
    {
        const size_t qoff = (size_t)(b * SEQ + qg) * HIDDEN + h * HDIM;
#pragma unroll
        for (int ds = 0; ds < 4; ++ds) qf[ds] = *(const bf16x8*)(qraw + qoff + ds * 32 + g * 8);
    }
    f32x4 acc_o[8] = {};
    float m_run = -1e30f, l_run = 0.f;
    u16* pw = &Pl[w][0];
    const size_t mrow = ((size_t)y * SEQ + qg) * SEQ;
    for (int kt = 0; kt <= qt; ++kt) {
        const int k0 = kt * 64;
#pragma unroll
        for (int c = 0; c < 4; ++c)
            gld_lds16(kraw + (size_t)(b * SEQ + k0 + c * 16 + k_srow) * HIDDEN + h * HDIM + k_scol,
                      &Ks[c * 2048 + tid * 8]);
#pragma unroll
        for (int c = 0; c < 4; ++c)
            gld_lds16(vT + (size_t)(y * HDIM + c * 32 + v_srow) * SEQ + k0 + v_scol,
                      &Vs[c * 2048 + tid * 8]);
        __syncthreads();
        // S^T = K * Q^T
        f32x4 accs[4] = {};
#pragma unroll
        for (int ds = 0; ds < 4; ++ds) {
#pragma unroll
            for (int m = 0; m < 4; ++m) {
                bf16x8 kf = *(const bf16x8*)&Ks[(m * 16 + q15) * 128 + ((ds * 32 + g * 8) ^ sw)];
                accs[m] = __builtin_amdgcn_mfma_f32_16x16x32_bf16(kf, qf[ds], accs[m], 0, 0, 0);
            }
        }
        // bias + causal + online softmax (value (m,r) <-> k = k0+m*16+g*4+r, q = qg)
        float p[4][4];
        float pmax = -1e30f;
#pragma unroll
        for (int m = 0; m < 4; ++m) {
            const size_t moff = mrow + k0 + m * 16 + g * 4;
            const float4 b1 = *(const float4*)(pm + moff);
            const float4 b2 = *(const float4*)(po + moff);
            const float4 b3 = *(const float4*)(mw + moff);
#pragma unroll
            for (int r = 0; r < 4; ++r) {
                const int kglob = k0 + m * 16 + g * 4 + r;
                const float bias = (&b1.x)[r] * (GSC * 0.5f) + (&b2.x)[r] * GSC +
                                   __logf(fmaf((&b3.x)[r], GSC, 1.0f + 1e-8f));
                float s = (kglob <= qg) ? fmaf(accs[m][r], SCALE, bias) : -1e30f;
                p[m][r] = s;
                pmax = fmaxf(pmax, s);
            }
        }
        pmax = fmaxf(pmax, __shfl_xor(pmax, 16));
        pmax = fmaxf(pmax, __shfl_xor(pmax, 32));
        const float mnew = fmaxf(m_run, pmax);
        const float alpha = __expf(m_run - mnew);
        float lsum = 0.f;
#pragma unroll
        for (int m = 0; m < 4; ++m)
#pragma unroll
            for (int r = 0; r < 4; ++r) {
                float e = __expf(p[m][r] - mnew);
                p[m][r] = e;
                lsum += e;
            }
        lsum += __shfl_xor(lsum, 16);
        lsum += __shfl_xor(lsum, 32);
        l_run = l_run * alpha + lsum;
        m_run = mnew;
        // P -> per-wave LDS [16 q][64 k] (stride 72)
#pragma unroll
        for (int m = 0; m < 4; ++m) {
            uint2 pk;
            pk.x = (u32)f2bf(p[m][0]) | ((u32)f2bf(p[m][1]) << 16);
            pk.y = (u32)f2bf(p[m][2]) | ((u32)f2bf(p[m][3]) << 16);
            *(uint2*)&pw[q15 * 72 + m * 16 + g * 4] = pk;
        }
        // rescale accumulator rows (rows are q = g*4+j in C/D layout)
        float al[4];
#pragma unroll
        for (int j = 0; j < 4; ++j) al[j] = __shfl(alpha, g * 4 + j);
#pragma unroll
        for (int n = 0; n < 8; ++n)
#pragma unroll
            for (int j = 0; j < 4; ++j) acc_o[n][j] *= al[j];
        // PV: A = P[q][k] (LDS), B = V^T[d][k] (LDS, swizzled)
#pragma unroll
        for (int c = 0; c < 2; ++c) {
            const bf16x8 af = *(const bf16x8*)&pw[q15 * 72 + c * 32 + g * 8];
#pragma unroll
            for (int n = 0; n < 8; ++n) {
                const bf16x8 vf = *(const bf16x8*)&Vs[(n * 16 + q15) * 64 + ((c * 32 + g * 8) ^ sw)];
                acc_o[n] = __builtin_amdgcn_mfma_f32_16x16x32_bf16(af, vf, acc_o[n], 0, 0, 0);
            }
        }
        __syncthreads();
    }
    const float linv = 1.0f / l_run;
    float li[4];
#pragma unroll
    for (int j = 0; j < 4; ++j) li[j] = __shfl(linv, g * 4 + j);
#pragma unroll
    for (int n = 0; n < 8; ++n)
#pragma unroll
        for (int j = 0; j < 4; ++j) {
            const int row = b * SEQ + qw + g * 4 + j;
            const int col = h * HDIM + n * 16 + q15;
            attnb[(size_t)row * HIDDEN + col] = f2bf(acc_o[n][j] * li[j]);
        }
}

extern "C" void kernel_launch(void* const* d_in, const int* in_sizes, int n_in,
                              void* d_out, int out_size, void* d_ws, size_t ws_size,
                              hipStream_t stream) {
    (void)in_sizes; (void)n_in; (void)out_size; (void)ws_size;
    const float* x  = (const float*)d_in[0];
    const float* pm = (const float*)d_in[1];
    const float* po = (const float*)d_in[2];
    const float* mw = (const float*)d_in[3];
    const float* Wq = (const float*)d_in[4];
    const float* Wk = (const float*)d_in[5];
    const float* Wv = (const float*)d_in[6];
    const float* Wo = (const float*)d_in[7];
    const float* bo = (const float*)d_in[8];
    float* out = (float*)d_out;

    char* ws = (char*)d_ws;
    const size_t SZ = (size_t)ROWS * HIDDEN;     // 4M elements
    const size_t OFF = SZ * 2;                   // 8 MB per bf16 buffer
    u16* xb    = (u16*)(ws + 0 * OFF);
    u16* Wqt   = (u16*)(ws + 1 * OFF);
    u16* Wkt   = (u16*)(ws + 2 * OFF);
    u16* Wvt   = (u16*)(ws + 3 * OFF);
    u16* Wot   = (u16*)(ws + 4 * OFF);
    u16* qrawp = (u16*)(ws + 5 * OFF);
    u16* krawp = (u16*)(ws + 6 * OFF);
    u16* vrawp = (u16*)(ws + 7 * OFF);
    u16* vTp   = (u16*)(ws + 8 * OFF);
    u16* attnb = (u16*)(ws + 9 * OFF);
    float* cosT = (float*)(ws + 10 * OFF);
    float* sinT = (float*)(ws + 10 * OFF + 262144);

    k_cvt<<<dim3((int)(SZ / 1024)), 256, 0, stream>>>(x, xb, (int)SZ);
    k_wt<<<dim3(64, 64), dim3(32, 8), 0, stream>>>(Wq, Wqt);
    k_wt<<<dim3(64, 64), dim3(32, 8), 0, stream>>>(Wk, Wkt);
    k_wt<<<dim3(64, 64), dim3(32, 8), 0, stream>>>(Wv, Wvt);
    k_wt<<<dim3(64, 64), dim3(32, 8), 0, stream>>>(Wo, Wot);
    k_rope_tab<<<256, 256, 0, stream>>>(cosT, sinT);
    k_gemm<0><<<dim3(16, 16, 3), 256, 0, stream>>>(xb, Wqt, Wkt, Wvt,
                                                   qrawp, krawp, vrawp, nullptr, nullptr);
    k_rope_apply<<<8192, 256, 0, stream>>>(qrawp, krawp, cosT, sinT);
    k_vt<<<dim3(32, 4, 32), dim3(32, 8), 0, stream>>>(vrawp, vTp);
    k_attn<<<dim3(16, 32), 256, 0, stream>>>(qrawp, krawp, vTp, pm, po, mw, attnb);
    k_gemm<1><<<dim3(16, 16, 1), 256, 0, stream>>>(attnb, Wot, nullptr, nullptr,
                                                   nullptr, nullptr, nullptr, out, bo);
}